// Round 7
// baseline (158.789 us; speedup 1.0000x reference)
//
#include <hip/hip_runtime.h>
#include <hip/hip_bf16.h>
#include <cstdint>
#include <cstddef>

#define N_ROWS 8192
#define DIM    512
#define NKT    8          // K-tiles of 64
#define C_EXPSCALE 14.4269504088896340736f   // 10*log2(e); exp(sim-10)=exp2((cos-1)*this)

typedef __attribute__((ext_vector_type(8))) short bf16x8;
typedef __attribute__((ext_vector_type(4))) float f32x4;

__device__ __forceinline__ ushort f2bf(float x) {
  union { float f; uint32_t u; } c; c.f = x;
  uint32_t r = (c.u + 0x7fffu + ((c.u >> 16) & 1u)) >> 16;
  return (ushort)r;
}

// ---------------- prep: fp32 row norms, fp32 diag, bf16 normalized copies ----
__global__ __launch_bounds__(256) void prep_kernel(const float* __restrict__ V,
                                                   const float* __restrict__ U,
                                                   ushort* __restrict__ Vn,
                                                   ushort* __restrict__ Un,
                                                   float* __restrict__ diag,
                                                   float* __restrict__ row_sum,
                                                   float* __restrict__ col_sum) {
  const int row = blockIdx.x * 4 + (threadIdx.x >> 6);
  const int l = threadIdx.x & 63;
  const float4* v4 = (const float4*)(V + (size_t)row * DIM) + l * 2;
  const float4* u4 = (const float4*)(U + (size_t)row * DIM) + l * 2;
  float4 a0 = v4[0], a1 = v4[1];
  float4 b0 = u4[0], b1 = u4[1];
  float sv = a0.x*a0.x + a0.y*a0.y + a0.z*a0.z + a0.w*a0.w
           + a1.x*a1.x + a1.y*a1.y + a1.z*a1.z + a1.w*a1.w;
  float su = b0.x*b0.x + b0.y*b0.y + b0.z*b0.z + b0.w*b0.w
           + b1.x*b1.x + b1.y*b1.y + b1.z*b1.z + b1.w*b1.w;
  float sd = a0.x*b0.x + a0.y*b0.y + a0.z*b0.z + a0.w*b0.w
           + a1.x*b1.x + a1.y*b1.y + a1.z*b1.z + a1.w*b1.w;
#pragma unroll
  for (int m = 1; m < 64; m <<= 1) {
    sv += __shfl_xor(sv, m, 64);
    su += __shfl_xor(su, m, 64);
    sd += __shfl_xor(sd, m, 64);
  }
  const float rv = 1.0f / fmaxf(sqrtf(sv), 1e-8f);
  const float ru = 1.0f / fmaxf(sqrtf(su), 1e-8f);
  if (l == 0) {
    diag[row] = sd * rv * ru * 10.0f;
    row_sum[row] = 0.0f;
    col_sum[row] = 0.0f;
  }

  const float av[8] = {a0.x, a0.y, a0.z, a0.w, a1.x, a1.y, a1.z, a1.w};
  const float bv[8] = {b0.x, b0.y, b0.z, b0.w, b1.x, b1.y, b1.z, b1.w};
  union { ushort us[8]; uint4 q; } pv, pu;
#pragma unroll
  for (int j = 0; j < 8; ++j) {
    pv.us[j] = f2bf(av[j] * rv);
    pu.us[j] = f2bf(bv[j] * ru);
  }
  *(uint4*)(Vn + (size_t)row * DIM + l * 8) = pv.q;
  *(uint4*)(Un + (size_t)row * DIM + l * 8) = pu.q;
}

// ---- PERSISTENT 256x256 GEMM (bf16 MFMA) + exp(sim-10) + row/col sums ----
// 256 blocks (1/CU), each owns 4 output tiles: ct FIXED (B panel L2-pinned),
// rt walks windows of 8 per g (per-XCD per-g set: A 2MB + B 1MB = 3MB < L2).
// The K-loop staging retargets j+2>=8 to the NEXT tile's K-tiles 0,1 ->
// uniform vmcnt(8) ledger across all 32 K-tiles; pipeline never drains
// (only tail: g=3,j=6 vmcnt(0)). Next tile's loads land under the epilogue.
// kk-OUTERMOST MFMA order per quad: 8 independent MFMAs between the two
// chained updates of an acc element (was back-to-back dependent pairs);
// per-element accumulation order (kk0 then kk1, K-tiles 0..7) unchanged ->
// bit-exact vs prior rounds.
// col_sum accumulated in registers across g (1 atomic, same-XCD contenders).
#define AREG(s,h) ((s)*32768 + (h)*16384)
#define BREG(s,h) (65536 + (s)*32768 + (h)*16384)

__global__ __launch_bounds__(512, 2) void gemm_lse_kernel(const ushort* __restrict__ Vn,
                                                          const ushort* __restrict__ Un,
                                                          float* __restrict__ row_sum,
                                                          float* __restrict__ col_sum) {
  __shared__ ushort Tile[65536];   // 128 KiB staging
  __shared__ float  Red[1536];     // 6 KiB epilogue reductions (separate: no WAR with staging)

  const int tid  = threadIdx.x;
  const int lane = tid & 63;
  const int wid  = tid >> 6;
  const int wm   = wid >> 2;       // 0..1
  const int wn   = wid & 3;        // 0..3
  const int l15  = lane & 15;
  const int lhi  = lane >> 4;      // 0..3
  const int sw7  = l15 & 7;

  // persistent map: 256 blocks = 8 xcd x 32 x; ct = xcd*4 + (x>>3) fixed;
  // rt(g) = (x&7) + 8g
  const int bid  = blockIdx.x;
  const int xcd  = bid & 7;
  const int x    = bid >> 3;               // 0..31
  const int ct   = xcd * 4 + (x >> 3);
  const int bc   = ct << 8;
  const int rbase = x & 7;

  // ---- per-lane staging geometry ----
  const int r0 = tid >> 3,          seg0 = (tid & 7) ^ (r0 & 7);
  const int r1 = (512 + tid) >> 3,  seg1 = ((512 + tid) & 7) ^ (r1 & 7);

  // B stage pointers: constant across g (ct fixed)
  const ushort* gB0_0 = Un + (size_t)(bc + r0) * DIM + seg0 * 8;
  const ushort* gB0_1 = Un + (size_t)(bc + r1) * DIM + seg1 * 8;
  const ushort* gB1_0 = Un + (size_t)(bc + 128 + r0) * DIM + seg0 * 8;
  const ushort* gB1_1 = Un + (size_t)(bc + 128 + r1) * DIM + seg1 * 8;

  auto stg = [&](const ushort* g0, const ushort* g1, int kt, int region) {
    __builtin_amdgcn_global_load_lds(
        (const __attribute__((address_space(1))) unsigned int*)(g0 + kt * 64),
        (__attribute__((address_space(3))) unsigned int*)((char*)Tile + region + wid * 1024),
        16, 0, 0);
    __builtin_amdgcn_global_load_lds(
        (const __attribute__((address_space(1))) unsigned int*)(g1 + kt * 64),
        (__attribute__((address_space(3))) unsigned int*)((char*)Tile + region + 8192 + wid * 1024),
        16, 0, 0);
  };
  auto aPtr0 = [&](int br_) { return Vn + (size_t)(br_ + r0) * DIM + seg0 * 8; };
  auto aPtr1 = [&](int br_) { return Vn + (size_t)(br_ + r1) * DIM + seg1 * 8; };

  // ---- hoisted LDS read bases; slot(kk=1) = slot(kk=0)^4 ----
  const char* TB = (const char*)Tile;
  const int aoff = wm * 16384 + l15 * 128;
  const int boff = (wn >> 1) * 16384 + ((wn & 1) * 64 + l15) * 128;
  const int sl0  = ((0 | lhi) ^ sw7) * 16;
  const int sl1  = ((4 | lhi) ^ sw7) * 16;
  const char* pA[2][2] = { { TB + aoff + sl0,          TB + aoff + sl1 },
                           { TB + 32768 + aoff + sl0,  TB + 32768 + aoff + sl1 } };
  const char* pB[2][2] = { { TB + 65536 + boff + sl0,  TB + 65536 + boff + sl1 },
                           { TB + 98304 + boff + sl0,  TB + 98304 + boff + sl1 } };

  f32x4 acc[8][4];

  // current-g A stage pointers (rt = rbase for g=0)
  const ushort* aC0_0 = aPtr0(rbase << 8);
  const ushort* aC0_1 = aPtr1(rbase << 8);
  const ushort* aC1_0 = aPtr0((rbase << 8) + 128);
  const ushort* aC1_1 = aPtr1((rbase << 8) + 128);

  float colTot = 0.0f;

  // prologue (once per kernel): tile0 + tile1 of g=0 in flight
  stg(aC0_0, aC0_1, 0, AREG(0, 0)); stg(aC1_0, aC1_1, 0, AREG(0, 1));
  stg(gB0_0, gB0_1, 0, BREG(0, 0)); stg(gB1_0, gB1_1, 0, BREG(0, 1));
  stg(aC0_0, aC0_1, 1, AREG(1, 0)); stg(aC1_0, aC1_1, 1, AREG(1, 1));
  stg(gB0_0, gB0_1, 1, BREG(1, 0)); stg(gB1_0, gB1_1, 1, BREG(1, 1));
  asm volatile("s_waitcnt vmcnt(8)" ::: "memory");
  __builtin_amdgcn_s_barrier();
  asm volatile("" ::: "memory");

  for (int g = 0; g < 4; ++g) {
    const int br = (rbase + 8 * g) << 8;
    const int brn = ((rbase + 8 * (g + 1)) & 31) << 8;   // next-g A (wrapped; unused at g=3)
    const ushort* aN0_0 = aPtr0(brn);
    const ushort* aN0_1 = aPtr1(brn);
    const ushort* aN1_0 = aPtr0(brn + 128);
    const ushort* aN1_1 = aPtr1(brn + 128);
    const bool gmore = (g < 3);

#pragma unroll
    for (int m = 0; m < 8; ++m)
#pragma unroll
      for (int n = 0; n < 4; ++n) acc[m][n] = (f32x4){0.f, 0.f, 0.f, 0.f};

#pragma unroll
    for (int j = 0; j < NKT; ++j) {
      const int b = j & 1;

      bf16x8 Af[8][2], Bf[4][2];
#pragma unroll
      for (int n = 0; n < 4; ++n) {
        Bf[n][0] = *(const bf16x8*)(pB[b][0] + n * 2048);
        Bf[n][1] = *(const bf16x8*)(pB[b][1] + n * 2048);
      }
#pragma unroll
      for (int m = 0; m < 4; ++m) {
        Af[m][0] = *(const bf16x8*)(pA[b][0] + m * 2048);
        Af[m][1] = *(const bf16x8*)(pA[b][1] + m * 2048);
      }

      // quad 0 (m0-1): kk-outermost (8 indep MFMAs between chained acc uses)
      __builtin_amdgcn_s_setprio(1);
#pragma unroll
      for (int kk = 0; kk < 2; ++kk)
#pragma unroll
        for (int m = 0; m < 2; ++m)
#pragma unroll
          for (int n = 0; n < 4; ++n)
            acc[m][n] = __builtin_amdgcn_mfma_f32_16x16x32_bf16(Af[m][kk], Bf[n][kk], acc[m][n], 0, 0, 0);
      __builtin_amdgcn_s_setprio(0);

#pragma unroll
      for (int m = 4; m < 8; ++m) {
        Af[m][0] = *(const bf16x8*)(pA[b][0] + m * 2048);
        Af[m][1] = *(const bf16x8*)(pA[b][1] + m * 2048);
      }

      // quads 1-2 (m2-5), kk-outermost
      __builtin_amdgcn_s_setprio(1);
#pragma unroll
      for (int kk = 0; kk < 2; ++kk)
#pragma unroll
        for (int m = 2; m < 6; ++m)
#pragma unroll
          for (int n = 0; n < 4; ++n)
            acc[m][n] = __builtin_amdgcn_mfma_f32_16x16x32_bf16(Af[m][kk], Bf[n][kk], acc[m][n], 0, 0, 0);
      __builtin_amdgcn_s_setprio(0);

      // WAR fence + stage over buf b: tiles j+2 of this g, or tiles 0,1 of next g
      if (j < NKT - 2) {
        asm volatile("s_waitcnt lgkmcnt(0)" ::: "memory");
        __builtin_amdgcn_s_barrier();
        asm volatile("" ::: "memory");
        stg(aC0_0, aC0_1, j + 2, AREG(b, 0)); stg(aC1_0, aC1_1, j + 2, AREG(b, 1));
        stg(gB0_0, gB0_1, j + 2, BREG(b, 0)); stg(gB1_0, gB1_1, j + 2, BREG(b, 1));
      } else if (gmore) {
        asm volatile("s_waitcnt lgkmcnt(0)" ::: "memory");
        __builtin_amdgcn_s_barrier();
        asm volatile("" ::: "memory");
        const int kt = j - (NKT - 2);       // 0 or 1
        stg(aN0_0, aN0_1, kt, AREG(b, 0)); stg(aN1_0, aN1_1, kt, AREG(b, 1));
        stg(gB0_0, gB0_1, kt, BREG(b, 0)); stg(gB1_0, gB1_1, kt, BREG(b, 1));
      }

      // quad 3 (m6-7), kk-outermost -- overlaps stage issue
      __builtin_amdgcn_s_setprio(1);
#pragma unroll
      for (int kk = 0; kk < 2; ++kk)
#pragma unroll
        for (int m = 6; m < 8; ++m)
#pragma unroll
          for (int n = 0; n < 4; ++n)
            acc[m][n] = __builtin_amdgcn_mfma_f32_16x16x32_bf16(Af[m][kk], Bf[n][kk], acc[m][n], 0, 0, 0);
      __builtin_amdgcn_s_setprio(0);

      // drain: next tile's loads complete
      if (j < NKT - 1 || gmore) {
        if (j == NKT - 2 && !gmore) {
          asm volatile("s_waitcnt vmcnt(0)" ::: "memory");
        } else {
          asm volatile("s_waitcnt vmcnt(8)" ::: "memory");
        }
        __builtin_amdgcn_s_barrier();
        asm volatile("" ::: "memory");
      }
    }

    // ---- epilogue for tile g: exp(sim-10), row/col partial sums ----
#pragma unroll
    for (int m = 0; m < 8; ++m)
#pragma unroll
      for (int n = 0; n < 4; ++n) {
        f32x4 v = acc[m][n];
#pragma unroll
        for (int r = 0; r < 4; ++r) v[r] = __builtin_amdgcn_exp2f((v[r] - 1.0f) * C_EXPSCALE);
        acc[m][n] = v;
      }

#pragma unroll
    for (int m = 0; m < 8; ++m)
#pragma unroll
      for (int r = 0; r < 4; ++r) {
        float s = acc[m][0][r] + acc[m][1][r] + acc[m][2][r] + acc[m][3][r];
        s += __shfl_xor(s, 1, 64);
        s += __shfl_xor(s, 2, 64);
        s += __shfl_xor(s, 4, 64);
        s += __shfl_xor(s, 8, 64);
        if (l15 == 0) Red[wn * 256 + wm * 128 + m * 16 + lhi * 4 + r] = s;
      }
#pragma unroll
    for (int n = 0; n < 4; ++n) {
      float s = 0.f;
#pragma unroll
      for (int m = 0; m < 8; ++m)
        s += acc[m][n][0] + acc[m][n][1] + acc[m][n][2] + acc[m][n][3];
      s += __shfl_xor(s, 16, 64);
      s += __shfl_xor(s, 32, 64);
      if (lane < 16) Red[1024 + wm * 256 + wn * 64 + n * 16 + lane] = s;
    }
    __syncthreads();

    if (tid < 256) {
      float s = Red[tid] + Red[256 + tid] + Red[512 + tid] + Red[768 + tid];
      atomicAdd(&row_sum[br + tid], s);          // per-g (br changes)
    } else {
      const int c = tid - 256;
      colTot += Red[1024 + c] + Red[1280 + c];   // bc fixed: accumulate
      if (g == 3) atomicAdd(&col_sum[bc + c], colTot);
    }

    // rotate A pointers to next g
    aC0_0 = aN0_0; aC0_1 = aN0_1; aC1_0 = aN1_0; aC1_1 = aN1_1;
  }
}

// ---------------- finalize ----------------
__global__ __launch_bounds__(1024) void finalize_kernel(const float* __restrict__ row_sum,
                                                        const float* __restrict__ col_sum,
                                                        const float* __restrict__ diag,
                                                        float* __restrict__ out) {
  __shared__ float sred[1024];
  float acc = 0.0f;
  for (int i = threadIdx.x; i < N_ROWS; i += 1024) {
    const float lse_r = 10.0f + logf(row_sum[i]);
    const float lse_c = 10.0f + logf(col_sum[i]);
    acc += 0.75f * lse_r + 0.25f * lse_c - diag[i];
  }
  sred[threadIdx.x] = acc;
  __syncthreads();
  for (int s = 512; s > 0; s >>= 1) {
    if ((int)threadIdx.x < s) sred[threadIdx.x] += sred[threadIdx.x + s];
    __syncthreads();
  }
  if (threadIdx.x == 0) out[0] = sred[0] / (float)N_ROWS;
}

extern "C" void kernel_launch(void* const* d_in, const int* in_sizes, int n_in,
                              void* d_out, int out_size, void* d_ws, size_t ws_size,
                              hipStream_t stream) {
  const float* V = (const float*)d_in[0];
  const float* U = (const float*)d_in[1];
  float* out = (float*)d_out;

  char* ws = (char*)d_ws;
  ushort* Vn      = (ushort*)(ws);
  ushort* Un      = (ushort*)(ws + 8388608);
  float*  diag    = (float*)(ws + 16777216);
  float*  row_sum = (float*)(ws + 16777216 + 32768);
  float*  col_sum = (float*)(ws + 16777216 + 65536);

  prep_kernel<<<N_ROWS / 4, 256, 0, stream>>>(V, U, Vn, Un, diag, row_sum, col_sum);
  gemm_lse_kernel<<<256, 512, 0, stream>>>(Vn, Un, row_sum, col_sum);
  finalize_kernel<<<1, 1024, 0, stream>>>(row_sum, col_sum, diag, out);
}

// Round 8
// 112.013 us; speedup vs baseline: 1.4176x; 1.4176x over previous
//
#include <hip/hip_runtime.h>
#include <hip/hip_bf16.h>
#include <cstdint>
#include <cstddef>

#define N_ROWS 8192
#define DIM    512
#define NKT    8          // K-tiles of 64
#define C_EXPSCALE 14.4269504088896340736f   // 10*log2(e); exp(sim-10)=exp2((cos-1)*this)

typedef __attribute__((ext_vector_type(8))) short bf16x8;
typedef __attribute__((ext_vector_type(4))) float f32x4;

__device__ __forceinline__ ushort f2bf(float x) {
  union { float f; uint32_t u; } c; c.f = x;
  uint32_t r = (c.u + 0x7fffu + ((c.u >> 16) & 1u)) >> 16;
  return (ushort)r;
}

// ---------------- prep: fp32 row norms, fp32 diag, bf16 normalized copies ----
__global__ __launch_bounds__(256) void prep_kernel(const float* __restrict__ V,
                                                   const float* __restrict__ U,
                                                   ushort* __restrict__ Vn,
                                                   ushort* __restrict__ Un,
                                                   float* __restrict__ diag,
                                                   float* __restrict__ row_sum,
                                                   float* __restrict__ col_sum) {
  const int row = blockIdx.x * 4 + (threadIdx.x >> 6);
  const int l = threadIdx.x & 63;
  const float4* v4 = (const float4*)(V + (size_t)row * DIM) + l * 2;
  const float4* u4 = (const float4*)(U + (size_t)row * DIM) + l * 2;
  float4 a0 = v4[0], a1 = v4[1];
  float4 b0 = u4[0], b1 = u4[1];
  float sv = a0.x*a0.x + a0.y*a0.y + a0.z*a0.z + a0.w*a0.w
           + a1.x*a1.x + a1.y*a1.y + a1.z*a1.z + a1.w*a1.w;
  float su = b0.x*b0.x + b0.y*b0.y + b0.z*b0.z + b0.w*b0.w
           + b1.x*b1.x + b1.y*b1.y + b1.z*b1.z + b1.w*b1.w;
  float sd = a0.x*b0.x + a0.y*b0.y + a0.z*b0.z + a0.w*b0.w
           + a1.x*b1.x + a1.y*b1.y + a1.z*b1.z + a1.w*b1.w;
#pragma unroll
  for (int m = 1; m < 64; m <<= 1) {
    sv += __shfl_xor(sv, m, 64);
    su += __shfl_xor(su, m, 64);
    sd += __shfl_xor(sd, m, 64);
  }
  const float rv = 1.0f / fmaxf(sqrtf(sv), 1e-8f);
  const float ru = 1.0f / fmaxf(sqrtf(su), 1e-8f);
  if (l == 0) {
    diag[row] = sd * rv * ru * 10.0f;
    row_sum[row] = 0.0f;
    col_sum[row] = 0.0f;
  }

  const float av[8] = {a0.x, a0.y, a0.z, a0.w, a1.x, a1.y, a1.z, a1.w};
  const float bv[8] = {b0.x, b0.y, b0.z, b0.w, b1.x, b1.y, b1.z, b1.w};
  union { ushort us[8]; uint4 q; } pv, pu;
#pragma unroll
  for (int j = 0; j < 8; ++j) {
    pv.us[j] = f2bf(av[j] * rv);
    pu.us[j] = f2bf(bv[j] * ru);
  }
  *(uint4*)(Vn + (size_t)row * DIM + l * 8) = pv.q;
  *(uint4*)(Un + (size_t)row * DIM + l * 8) = pu.q;
}

// ---- 256x128 GEMM (bf16 MFMA) + exp(sim-10) + row/col sums ----
// REGISTER-PIPELINED: wave tile 64x64 (acc 64 AGPR) frees 128 VGPR for TWO
// full fragment sets -> frags(j+1) ds_read from LDS WHILE frags(j) (already
// in registers) feed 32 MFMAs. The MFMA window has ZERO blocking waits; the
// lockstep read-storm/MFMA-burst alternation (the invariant across R1-R6's
// identical 86us) is broken at the wave level.
// Per K-tile j (buf b=j&1):
//   boundary: lgkm0+bar (WAR: buf-b reads retired) | stage(j+2 -> buf b, 6)
//             | vmcnt(6)+bar (tile j+1 landed in buf b^1)
//   body:     ds_read frags(j+1) <- buf b^1 (16 b128, no pins)
//             || 32 MFMA on frags(j)   [compiler interleaves]
// Ledger: prologue 12 (tiles 0,1), vmcnt(6); j<=5 stage +6, vmcnt(6) drains
// tile j+1; j=6 vmcnt(0); j=7 compute-only. Per-element accumulation order
// (kk0,kk1; tiles 0..7) unchanged -> bit-exact.
// Map: xcd owns fixed 8-ct stripe (B 1MB L2-resident); rt streams 4/round
// (A 1MB/round) -> 2MB round set, L2-resident.
__global__ __launch_bounds__(512, 2) void gemm_lse_kernel(const ushort* __restrict__ Vn,
                                                          const ushort* __restrict__ Un,
                                                          float* __restrict__ row_sum,
                                                          float* __restrict__ col_sum) {
  // buf0: A@0 (32K) B@32768 (16K); buf1: A@49152 B@81920; Red@98304 (4K)
  __shared__ ushort Tile[51200];   // 100 KiB

  const int tid  = threadIdx.x;
  const int lane = tid & 63;
  const int wid  = tid >> 6;
  const int wr   = wid >> 1;       // 0..3 (64-row band)
  const int wc   = wid & 1;        // 0..1 (64-col band)
  const int l15  = lane & 15;
  const int lhi  = lane >> 4;      // 0..3
  const int sw7  = l15 & 7;

  // map: 2048 blocks = 8 xcd x 256; ct = xcd*8 + (x&7) fixed stripe; rt = x>>3
  const int bid  = blockIdx.x;
  const int xcd  = bid & 7;
  const int x    = bid >> 3;               // 0..255
  const int ct   = xcd * 8 + (x & 7);      // 0..63
  const int rt   = x >> 3;                 // 0..31
  const int br   = rt << 8;                // 256-row tile
  const int bc   = ct << 7;                // 128-col tile

  // ---- staging geometry: A 4 issues (32KB), B 2 issues (16KB) ----
  const int r0  = tid >> 3;                // 0..63
  const int seg = (tid & 7) ^ (r0 & 7);    // inverse-swizzled source seg
  const ushort* gA[4]; const ushort* gB[2];
#pragma unroll
  for (int i = 0; i < 4; ++i) gA[i] = Vn + (size_t)(br + i * 64 + r0) * DIM + seg * 8;
#pragma unroll
  for (int i = 0; i < 2; ++i) gB[i] = Un + (size_t)(bc + i * 64 + r0) * DIM + seg * 8;

  auto stg6 = [&](int buf, int kt) {   // stage whole K-tile kt into buf (6 loads)
#pragma unroll
    for (int i = 0; i < 4; ++i)
      __builtin_amdgcn_global_load_lds(
          (const __attribute__((address_space(1))) unsigned int*)(gA[i] + kt * 64),
          (__attribute__((address_space(3))) unsigned int*)((char*)Tile + buf * 49152 + i * 8192 + wid * 1024),
          16, 0, 0);
#pragma unroll
    for (int i = 0; i < 2; ++i)
      __builtin_amdgcn_global_load_lds(
          (const __attribute__((address_space(1))) unsigned int*)(gB[i] + kt * 64),
          (__attribute__((address_space(3))) unsigned int*)((char*)Tile + buf * 49152 + 32768 + i * 8192 + wid * 1024),
          16, 0, 0);
  };

  // ---- LDS read bases; slot = ((kk<<2)|lhi)^sw7 ----
  const char* TB = (const char*)Tile;
  const int sl0  = ((0 | lhi) ^ sw7) * 16;
  const int sl1  = ((4 | lhi) ^ sw7) * 16;
  const int aoff = (wr * 64 + l15) * 128;
  const int boff = (wc * 64 + l15) * 128;
  const char* pA[2] = { TB + aoff,          TB + 49152 + aoff };
  const char* pB[2] = { TB + 32768 + boff,  TB + 81920 + boff };

  f32x4 acc[4][4];
#pragma unroll
  for (int m = 0; m < 4; ++m)
#pragma unroll
    for (int n = 0; n < 4; ++n) acc[m][n] = (f32x4){0.f, 0.f, 0.f, 0.f};

  bf16x8 FA[2][4][2], FB[2][4][2];   // [set][m|n][kk]; set = tile parity (static after unroll)

  // prologue: tiles 0,1 staged; frags(0) -> set0
  stg6(0, 0); stg6(1, 1);
  asm volatile("s_waitcnt vmcnt(6)" ::: "memory");   // tile0 landed
  __builtin_amdgcn_s_barrier();
  asm volatile("" ::: "memory");
#pragma unroll
  for (int m = 0; m < 4; ++m) {
    FA[0][m][0] = *(const bf16x8*)(pA[0] + m * 2048 + sl0);
    FA[0][m][1] = *(const bf16x8*)(pA[0] + m * 2048 + sl1);
  }
#pragma unroll
  for (int n = 0; n < 4; ++n) {
    FB[0][n][0] = *(const bf16x8*)(pB[0] + n * 2048 + sl0);
    FB[0][n][1] = *(const bf16x8*)(pB[0] + n * 2048 + sl1);
  }

#pragma unroll
  for (int j = 0; j < NKT; ++j) {
    const int b = j & 1;       // compile-time after unroll
    const int s = j & 1;       // current fragment set
    const int ns = s ^ 1;

    // ---- boundary ----
    if (j + 2 < NKT) {
      asm volatile("s_waitcnt lgkmcnt(0)" ::: "memory");   // buf-b reads (issued at j-1) retired
      __builtin_amdgcn_s_barrier();
      asm volatile("" ::: "memory");
      stg6(b, j + 2);                                      // overwrite buf b (tile j in regs)
      asm volatile("s_waitcnt vmcnt(6)" ::: "memory");     // tile j+1 landed in buf b^1
      __builtin_amdgcn_s_barrier();
      asm volatile("" ::: "memory");
    } else if (j == NKT - 2) {
      asm volatile("s_waitcnt lgkmcnt(0)" ::: "memory");
      __builtin_amdgcn_s_barrier();
      asm volatile("" ::: "memory");
      asm volatile("s_waitcnt vmcnt(0)" ::: "memory");     // tile 7 landed
      __builtin_amdgcn_s_barrier();
      asm volatile("" ::: "memory");
    }
    // j == NKT-1: no sync needed

    // ---- body: read frags(j+1) from buf b^1 (overlaps MFMAs below) ----
    if (j < NKT - 1) {
#pragma unroll
      for (int m = 0; m < 4; ++m) {
        FA[ns][m][0] = *(const bf16x8*)(pA[b ^ 1] + m * 2048 + sl0);
        FA[ns][m][1] = *(const bf16x8*)(pA[b ^ 1] + m * 2048 + sl1);
      }
#pragma unroll
      for (int n = 0; n < 4; ++n) {
        FB[ns][n][0] = *(const bf16x8*)(pB[b ^ 1] + n * 2048 + sl0);
        FB[ns][n][1] = *(const bf16x8*)(pB[b ^ 1] + n * 2048 + sl1);
      }
    }

    // 32 MFMAs on frags(j) -- already in registers, no waits
    __builtin_amdgcn_s_setprio(1);
#pragma unroll
    for (int kk = 0; kk < 2; ++kk)
#pragma unroll
      for (int m = 0; m < 4; ++m)
#pragma unroll
        for (int n = 0; n < 4; ++n)
          acc[m][n] = __builtin_amdgcn_mfma_f32_16x16x32_bf16(FA[s][m][kk], FB[s][n][kk], acc[m][n], 0, 0, 0);
    __builtin_amdgcn_s_setprio(0);
  }

  // ---- epilogue: exp(sim-10), row/col partial sums ----
  float* Red = (float*)((char*)Tile + 98304);   // 1024 floats

#pragma unroll
  for (int m = 0; m < 4; ++m)
#pragma unroll
    for (int n = 0; n < 4; ++n) {
      f32x4 v = acc[m][n];
#pragma unroll
      for (int r = 0; r < 4; ++r) v[r] = __builtin_amdgcn_exp2f((v[r] - 1.0f) * C_EXPSCALE);
      acc[m][n] = v;
    }

  // rows: row_local = wr*64 + m*16 + lhi*4 + r; sum over n then over 16 cols
#pragma unroll
  for (int m = 0; m < 4; ++m)
#pragma unroll
    for (int r = 0; r < 4; ++r) {
      float s = acc[m][0][r] + acc[m][1][r] + acc[m][2][r] + acc[m][3][r];
      s += __shfl_xor(s, 1, 64);
      s += __shfl_xor(s, 2, 64);
      s += __shfl_xor(s, 4, 64);
      s += __shfl_xor(s, 8, 64);
      if (l15 == 0) Red[wc * 256 + wr * 64 + m * 16 + lhi * 4 + r] = s;
    }
  // cols: col_local = wc*64 + n*16 + l15; sum over m,r then over 4 row-groups
#pragma unroll
  for (int n = 0; n < 4; ++n) {
    float s = 0.f;
#pragma unroll
    for (int m = 0; m < 4; ++m)
      s += acc[m][n][0] + acc[m][n][1] + acc[m][n][2] + acc[m][n][3];
    s += __shfl_xor(s, 16, 64);
    s += __shfl_xor(s, 32, 64);
    if (lane < 16) Red[512 + wr * 128 + wc * 64 + n * 16 + lane] = s;
  }
  __syncthreads();

  if (tid < 256) {
    atomicAdd(&row_sum[br + tid], Red[tid] + Red[256 + tid]);
  } else if (tid < 384) {
    const int c = tid - 256;
    atomicAdd(&col_sum[bc + c], Red[512 + c] + Red[640 + c] + Red[768 + c] + Red[896 + c]);
  }
}

// ---------------- finalize ----------------
__global__ __launch_bounds__(1024) void finalize_kernel(const float* __restrict__ row_sum,
                                                        const float* __restrict__ col_sum,
                                                        const float* __restrict__ diag,
                                                        float* __restrict__ out) {
  __shared__ float sred[1024];
  float acc = 0.0f;
  for (int i = threadIdx.x; i < N_ROWS; i += 1024) {
    const float lse_r = 10.0f + logf(row_sum[i]);
    const float lse_c = 10.0f + logf(col_sum[i]);
    acc += 0.75f * lse_r + 0.25f * lse_c - diag[i];
  }
  sred[threadIdx.x] = acc;
  __syncthreads();
  for (int s = 512; s > 0; s >>= 1) {
    if ((int)threadIdx.x < s) sred[threadIdx.x] += sred[threadIdx.x + s];
    __syncthreads();
  }
  if (threadIdx.x == 0) out[0] = sred[0] / (float)N_ROWS;
}

extern "C" void kernel_launch(void* const* d_in, const int* in_sizes, int n_in,
                              void* d_out, int out_size, void* d_ws, size_t ws_size,
                              hipStream_t stream) {
  const float* V = (const float*)d_in[0];
  const float* U = (const float*)d_in[1];
  float* out = (float*)d_out;

  char* ws = (char*)d_ws;
  ushort* Vn      = (ushort*)(ws);
  ushort* Un      = (ushort*)(ws + 8388608);
  float*  diag    = (float*)(ws + 16777216);
  float*  row_sum = (float*)(ws + 16777216 + 32768);
  float*  col_sum = (float*)(ws + 16777216 + 65536);

  prep_kernel<<<N_ROWS / 4, 256, 0, stream>>>(V, U, Vn, Un, diag, row_sum, col_sum);
  gemm_lse_kernel<<<(N_ROWS / 256) * (N_ROWS / 128), 512, 0, stream>>>(Vn, Un, row_sum, col_sum);
  finalize_kernel<<<1, 1024, 0, stream>>>(row_sum, col_sum, diag, out);
}

// Round 9
// 88.210 us; speedup vs baseline: 1.8001x; 1.2699x over previous
//
#include <hip/hip_runtime.h>
#include <hip/hip_bf16.h>
#include <cstdint>
#include <cstddef>

#define N_ROWS 8192
#define DIM    512
#define NKT    8          // K-tiles of 64
#define C_EXPSCALE 14.4269504088896340736f   // 10*log2(e); exp(sim-10)=exp2((cos-1)*this)

typedef __attribute__((ext_vector_type(8))) short bf16x8;
typedef __attribute__((ext_vector_type(4))) float f32x4;

__device__ __forceinline__ ushort f2bf(float x) {
  union { float f; uint32_t u; } c; c.f = x;
  uint32_t r = (c.u + 0x7fffu + ((c.u >> 16) & 1u)) >> 16;
  return (ushort)r;
}

// ---------------- prep: fp32 row norms, fp32 diag, bf16 normalized copies ----
__global__ __launch_bounds__(256) void prep_kernel(const float* __restrict__ V,
                                                   const float* __restrict__ U,
                                                   ushort* __restrict__ Vn,
                                                   ushort* __restrict__ Un,
                                                   float* __restrict__ diag,
                                                   float* __restrict__ row_sum,
                                                   float* __restrict__ col_sum) {
  const int row = blockIdx.x * 4 + (threadIdx.x >> 6);
  const int l = threadIdx.x & 63;
  const float4* v4 = (const float4*)(V + (size_t)row * DIM) + l * 2;
  const float4* u4 = (const float4*)(U + (size_t)row * DIM) + l * 2;
  float4 a0 = v4[0], a1 = v4[1];
  float4 b0 = u4[0], b1 = u4[1];
  float sv = a0.x*a0.x + a0.y*a0.y + a0.z*a0.z + a0.w*a0.w
           + a1.x*a1.x + a1.y*a1.y + a1.z*a1.z + a1.w*a1.w;
  float su = b0.x*b0.x + b0.y*b0.y + b0.z*b0.z + b0.w*b0.w
           + b1.x*b1.x + b1.y*b1.y + b1.z*b1.z + b1.w*b1.w;
  float sd = a0.x*b0.x + a0.y*b0.y + a0.z*b0.z + a0.w*b0.w
           + a1.x*b1.x + a1.y*b1.y + a1.z*b1.z + a1.w*b1.w;
#pragma unroll
  for (int m = 1; m < 64; m <<= 1) {
    sv += __shfl_xor(sv, m, 64);
    su += __shfl_xor(su, m, 64);
    sd += __shfl_xor(sd, m, 64);
  }
  const float rv = 1.0f / fmaxf(sqrtf(sv), 1e-8f);
  const float ru = 1.0f / fmaxf(sqrtf(su), 1e-8f);
  if (l == 0) {
    diag[row] = sd * rv * ru * 10.0f;
    row_sum[row] = 0.0f;
    col_sum[row] = 0.0f;
  }

  const float av[8] = {a0.x, a0.y, a0.z, a0.w, a1.x, a1.y, a1.z, a1.w};
  const float bv[8] = {b0.x, b0.y, b0.z, b0.w, b1.x, b1.y, b1.z, b1.w};
  union { ushort us[8]; uint4 q; } pv, pu;
#pragma unroll
  for (int j = 0; j < 8; ++j) {
    pv.us[j] = f2bf(av[j] * rv);
    pu.us[j] = f2bf(bv[j] * ru);
  }
  *(uint4*)(Vn + (size_t)row * DIM + l * 8) = pv.q;
  *(uint4*)(Un + (size_t)row * DIM + l * 8) = pu.q;
}

// ---- 256x256 GEMM (bf16 MFMA) + exp(sim-10) + row/col sums ----
// 16-WAVE / 4-WAVES-PER-SIMD variant. Every prior round ran 2 waves/SIMD
// (the cross-round invariant); this splits the same 256^2 tile across 16
// waves of 64x64 (acc 64 AGPR, VGPR fits the 128-reg tier via
// __launch_bounds__(1024,4)) -> 4 waves/SIMD from one block. Within each
// read-window 4 waves pipeline LDS; within each MFMA window 4 waves feed the
// matrix pipe; vmcnt waits hide under cross-wave drift. Staged bytes
// UNCHANGED (512 MB total; byte-optimal 256^2 tile, BK=64 double-buffer).
// Per K-tile j (buf b=j&1):
//   read kk0 frags (8 b128) ; 16 MFMA ; read kk1 ; 16 MFMA   [no pins]
//   lgkm0+bar (WAR) ; stg4(b, j+2) ; vmcnt(4)+bar (tile j+1 landed)
// Ledger: 4 glds/K-tile/thread; prologue 8 -> vmcnt(4) = tile0; each stage
// +4 -> vmcnt(4) drains j+1; j=6 vmcnt(0). Per-element accumulation order
// (kk0,kk1; K-tiles 0..7) unchanged -> bit-exact vs all prior rounds.
// Map (R6): xcd owns fixed 4-ct stripe (B 1MB L2-resident); rt streams.
__global__ __launch_bounds__(1024, 4) void gemm_lse_kernel(const ushort* __restrict__ Vn,
                                                           const ushort* __restrict__ Un,
                                                           float* __restrict__ row_sum,
                                                           float* __restrict__ col_sum) {
  // buf b at b*65536: A[256][64] @0 (32K), B[256][64] @32768 (32K... 32K A + 32K B)
  __shared__ ushort Tile[65536];   // 128 KiB

  const int tid  = threadIdx.x;
  const int lane = tid & 63;
  const int wid  = tid >> 6;       // 0..15
  const int wr   = wid >> 2;       // 0..3 (64-row band)
  const int wc   = wid & 3;        // 0..3 (64-col band)
  const int l15  = lane & 15;
  const int lhi  = lane >> 4;      // 0..3
  const int sw7  = l15 & 7;

  // L2-residency map (R6): xcd owns fixed 4-ct stripe; rt streams 8/round
  const int bid  = blockIdx.x;
  const int xcd  = bid & 7;
  const int x    = bid >> 3;               // 0..127
  const int rt   = x >> 2;                 // 0..31
  const int ct   = xcd * 4 + (x & 3);      // fixed stripe
  const int br   = rt << 8;
  const int bc   = ct << 8;

  // ---- staging geometry: per matrix per K-tile = 2 issues x 1024 thr x 16B ----
  const int rr  = tid >> 3;                // 0..127
  const int seg = (tid & 7) ^ (rr & 7);    // inverse-swizzled source seg
  const ushort* gA[2]; const ushort* gB[2];
#pragma unroll
  for (int i = 0; i < 2; ++i) {
    gA[i] = Vn + (size_t)(br + i * 128 + rr) * DIM + seg * 8;
    gB[i] = Un + (size_t)(bc + i * 128 + rr) * DIM + seg * 8;
  }

  auto stg4 = [&](int buf, int kt) {   // whole K-tile kt -> buf (4 glds/thread)
#pragma unroll
    for (int i = 0; i < 2; ++i)
      __builtin_amdgcn_global_load_lds(
          (const __attribute__((address_space(1))) unsigned int*)(gA[i] + kt * 64),
          (__attribute__((address_space(3))) unsigned int*)((char*)Tile + buf * 65536 + i * 16384 + wid * 1024),
          16, 0, 0);
#pragma unroll
    for (int i = 0; i < 2; ++i)
      __builtin_amdgcn_global_load_lds(
          (const __attribute__((address_space(1))) unsigned int*)(gB[i] + kt * 64),
          (__attribute__((address_space(3))) unsigned int*)((char*)Tile + buf * 65536 + 32768 + i * 16384 + wid * 1024),
          16, 0, 0);
  };

  // ---- LDS read bases; physical slot = ((kk<<2)|lhi) ^ sw7 ----
  const char* TB = (const char*)Tile;
  const int sl0  = ((0 | lhi) ^ sw7) * 16;
  const int sl1  = ((4 | lhi) ^ sw7) * 16;
  const int aoff = (wr * 64 + l15) * 128;
  const int boff = (wc * 64 + l15) * 128;
  const char* pA[2] = { TB + aoff,          TB + 65536 + aoff };
  const char* pB[2] = { TB + 32768 + boff,  TB + 98304 + boff };

  f32x4 acc[4][4];
#pragma unroll
  for (int m = 0; m < 4; ++m)
#pragma unroll
    for (int n = 0; n < 4; ++n) acc[m][n] = (f32x4){0.f, 0.f, 0.f, 0.f};

  // prologue: tiles 0,1 staged (8 glds); tile0 landed at vmcnt(4)
  stg4(0, 0); stg4(1, 1);
  asm volatile("s_waitcnt vmcnt(4)" ::: "memory");
  __builtin_amdgcn_s_barrier();
  asm volatile("" ::: "memory");

#pragma unroll
  for (int j = 0; j < NKT; ++j) {
    const int b = j & 1;

    bf16x8 A0[4], B0[4], A1[4], B1[4];
    // kk0: read + 16 MFMA (compiler interleaves with counted lgkm)
#pragma unroll
    for (int m = 0; m < 4; ++m) A0[m] = *(const bf16x8*)(pA[b] + m * 2048 + sl0);
#pragma unroll
    for (int n = 0; n < 4; ++n) B0[n] = *(const bf16x8*)(pB[b] + n * 2048 + sl0);
    __builtin_amdgcn_s_setprio(1);
#pragma unroll
    for (int m = 0; m < 4; ++m)
#pragma unroll
      for (int n = 0; n < 4; ++n)
        acc[m][n] = __builtin_amdgcn_mfma_f32_16x16x32_bf16(A0[m], B0[n], acc[m][n], 0, 0, 0);
    __builtin_amdgcn_s_setprio(0);

    // kk1: read + 16 MFMA
#pragma unroll
    for (int m = 0; m < 4; ++m) A1[m] = *(const bf16x8*)(pA[b] + m * 2048 + sl1);
#pragma unroll
    for (int n = 0; n < 4; ++n) B1[n] = *(const bf16x8*)(pB[b] + n * 2048 + sl1);
    __builtin_amdgcn_s_setprio(1);
#pragma unroll
    for (int m = 0; m < 4; ++m)
#pragma unroll
      for (int n = 0; n < 4; ++n)
        acc[m][n] = __builtin_amdgcn_mfma_f32_16x16x32_bf16(A1[m], B1[n], acc[m][n], 0, 0, 0);
    __builtin_amdgcn_s_setprio(0);

    // boundary
    if (j + 2 < NKT) {
      asm volatile("s_waitcnt lgkmcnt(0)" ::: "memory");   // frag reads retired -> buf b free
      __builtin_amdgcn_s_barrier();
      asm volatile("" ::: "memory");
      stg4(b, j + 2);
      asm volatile("s_waitcnt vmcnt(4)" ::: "memory");     // tile j+1 landed in buf b^1
      __builtin_amdgcn_s_barrier();
      asm volatile("" ::: "memory");
    } else if (j == NKT - 2) {
      asm volatile("s_waitcnt vmcnt(0)" ::: "memory");     // tile 7 landed
      __builtin_amdgcn_s_barrier();
      asm volatile("" ::: "memory");
    }
    // j == NKT-1: fall through to epilogue
  }

  // ---- epilogue: exp(sim-10), row/col partial sums ----
  // Red reuses buf0 bytes 0..8191 (buf0's last reads completed at j=6's fence;
  // j=7 reads buf1 only). RedR = Red[0..1023] (by wc), RedC = Red[1024..2047] (by wr).
  float* Red = (float*)Tile;

#pragma unroll
  for (int m = 0; m < 4; ++m)
#pragma unroll
    for (int n = 0; n < 4; ++n) {
      f32x4 v = acc[m][n];
#pragma unroll
      for (int r = 0; r < 4; ++r) v[r] = __builtin_amdgcn_exp2f((v[r] - 1.0f) * C_EXPSCALE);
      acc[m][n] = v;
    }

  // rows: row_local = wr*64 + m*16 + lhi*4 + r; sum over wave's 64 cols
#pragma unroll
  for (int m = 0; m < 4; ++m)
#pragma unroll
    for (int r = 0; r < 4; ++r) {
      float s = acc[m][0][r] + acc[m][1][r] + acc[m][2][r] + acc[m][3][r];
      s += __shfl_xor(s, 1, 64);
      s += __shfl_xor(s, 2, 64);
      s += __shfl_xor(s, 4, 64);
      s += __shfl_xor(s, 8, 64);
      if (l15 == 0) Red[wc * 256 + wr * 64 + m * 16 + lhi * 4 + r] = s;
    }
  // cols: col_local = wc*64 + n*16 + l15; sum over wave's 64 rows
#pragma unroll
  for (int n = 0; n < 4; ++n) {
    float s = 0.f;
#pragma unroll
    for (int m = 0; m < 4; ++m)
      s += acc[m][n][0] + acc[m][n][1] + acc[m][n][2] + acc[m][n][3];
    s += __shfl_xor(s, 16, 64);
    s += __shfl_xor(s, 32, 64);
    if (lane < 16) Red[1024 + wr * 256 + wc * 64 + n * 16 + lane] = s;
  }
  __syncthreads();

  if (tid < 256) {
    float s = Red[tid] + Red[256 + tid] + Red[512 + tid] + Red[768 + tid];
    atomicAdd(&row_sum[br + tid], s);
  } else if (tid < 512) {
    const int c = tid - 256;
    float s = Red[1024 + c] + Red[1280 + c] + Red[1536 + c] + Red[1792 + c];
    atomicAdd(&col_sum[bc + c], s);
  }
}

// ---------------- finalize ----------------
__global__ __launch_bounds__(1024) void finalize_kernel(const float* __restrict__ row_sum,
                                                        const float* __restrict__ col_sum,
                                                        const float* __restrict__ diag,
                                                        float* __restrict__ out) {
  __shared__ float sred[1024];
  float acc = 0.0f;
  for (int i = threadIdx.x; i < N_ROWS; i += 1024) {
    const float lse_r = 10.0f + logf(row_sum[i]);
    const float lse_c = 10.0f + logf(col_sum[i]);
    acc += 0.75f * lse_r + 0.25f * lse_c - diag[i];
  }
  sred[threadIdx.x] = acc;
  __syncthreads();
  for (int s = 512; s > 0; s >>= 1) {
    if ((int)threadIdx.x < s) sred[threadIdx.x] += sred[threadIdx.x + s];
    __syncthreads();
  }
  if (threadIdx.x == 0) out[0] = sred[0] / (float)N_ROWS;
}

extern "C" void kernel_launch(void* const* d_in, const int* in_sizes, int n_in,
                              void* d_out, int out_size, void* d_ws, size_t ws_size,
                              hipStream_t stream) {
  const float* V = (const float*)d_in[0];
  const float* U = (const float*)d_in[1];
  float* out = (float*)d_out;

  char* ws = (char*)d_ws;
  ushort* Vn      = (ushort*)(ws);
  ushort* Un      = (ushort*)(ws + 8388608);
  float*  diag    = (float*)(ws + 16777216);
  float*  row_sum = (float*)(ws + 16777216 + 32768);
  float*  col_sum = (float*)(ws + 16777216 + 65536);

  prep_kernel<<<N_ROWS / 4, 256, 0, stream>>>(V, U, Vn, Un, diag, row_sum, col_sum);
  gemm_lse_kernel<<<(N_ROWS / 256) * (N_ROWS / 256), 1024, 0, stream>>>(Vn, Un, row_sum, col_sum);
  finalize_kernel<<<1, 1024, 0, stream>>>(row_sum, col_sum, diag, out);
}

// Round 10
// 86.194 us; speedup vs baseline: 1.8422x; 1.0234x over previous
//
#include <hip/hip_runtime.h>
#include <hip/hip_bf16.h>
#include <cstdint>
#include <cstddef>

#define N_ROWS 8192
#define DIM    512
#define NKT    8          // K-tiles of 64
#define C_EXPSCALE 14.4269504088896340736f   // 10*log2(e); exp(sim-10)=exp2((cos-1)*this)

typedef __attribute__((ext_vector_type(8))) short bf16x8;
typedef __attribute__((ext_vector_type(4))) float f32x4;

__device__ __forceinline__ ushort f2bf(float x) {
  union { float f; uint32_t u; } c; c.f = x;
  uint32_t r = (c.u + 0x7fffu + ((c.u >> 16) & 1u)) >> 16;
  return (ushort)r;
}

// ---------------- prep: fp32 row norms, fp32 diag, bf16 normalized copies ----
__global__ __launch_bounds__(256) void prep_kernel(const float* __restrict__ V,
                                                   const float* __restrict__ U,
                                                   ushort* __restrict__ Vn,
                                                   ushort* __restrict__ Un,
                                                   float* __restrict__ diag,
                                                   float* __restrict__ row_sum,
                                                   float* __restrict__ col_sum) {
  const int row = blockIdx.x * 4 + (threadIdx.x >> 6);
  const int l = threadIdx.x & 63;
  const float4* v4 = (const float4*)(V + (size_t)row * DIM) + l * 2;
  const float4* u4 = (const float4*)(U + (size_t)row * DIM) + l * 2;
  float4 a0 = v4[0], a1 = v4[1];
  float4 b0 = u4[0], b1 = u4[1];
  float sv = a0.x*a0.x + a0.y*a0.y + a0.z*a0.z + a0.w*a0.w
           + a1.x*a1.x + a1.y*a1.y + a1.z*a1.z + a1.w*a1.w;
  float su = b0.x*b0.x + b0.y*b0.y + b0.z*b0.z + b0.w*b0.w
           + b1.x*b1.x + b1.y*b1.y + b1.z*b1.z + b1.w*b1.w;
  float sd = a0.x*b0.x + a0.y*b0.y + a0.z*b0.z + a0.w*b0.w
           + a1.x*b1.x + a1.y*b1.y + a1.z*b1.z + a1.w*b1.w;
#pragma unroll
  for (int m = 1; m < 64; m <<= 1) {
    sv += __shfl_xor(sv, m, 64);
    su += __shfl_xor(su, m, 64);
    sd += __shfl_xor(sd, m, 64);
  }
  const float rv = 1.0f / fmaxf(sqrtf(sv), 1e-8f);
  const float ru = 1.0f / fmaxf(sqrtf(su), 1e-8f);
  if (l == 0) {
    diag[row] = sd * rv * ru * 10.0f;
    row_sum[row] = 0.0f;
    col_sum[row] = 0.0f;
  }

  const float av[8] = {a0.x, a0.y, a0.z, a0.w, a1.x, a1.y, a1.z, a1.w};
  const float bv[8] = {b0.x, b0.y, b0.z, b0.w, b1.x, b1.y, b1.z, b1.w};
  union { ushort us[8]; uint4 q; } pv, pu;
#pragma unroll
  for (int j = 0; j < 8; ++j) {
    pv.us[j] = f2bf(av[j] * rv);
    pu.us[j] = f2bf(bv[j] * ru);
  }
  *(uint4*)(Vn + (size_t)row * DIM + l * 8) = pv.q;
  *(uint4*)(Un + (size_t)row * DIM + l * 8) = pu.q;
}

// ---- 256x256 GEMM (bf16 MFMA) + exp(sim-10) + row/col sums ----
// R9 (16 waves / 4 per SIMD) + SINGLE-BARRIER boundary.
// R9's boundary had two block-wide barrier drains per K-tile; both waits are
// cold (cover loads issued a full K-tile earlier), so the boundary collapses
// legally to ONE barrier:
//   s_waitcnt vmcnt(0) lgkmcnt(0) ; s_barrier ; stage(j+2 -> buf b)
// lgkm0-before-bar => all waves' reads of buf b retired => staging b after
// the bar is WAR-safe. vmcnt(0)-before-bar => every thread's tile-j+1 loads
// landed => reads of buf b^1 after the bar are safe. Staged loads fly across
// the whole next K-tile; drained by the NEXT boundary's cold vmcnt(0).
// Barriers: 16 -> 8 per block. Accumulation order unchanged (bit-identical).
// VGPR must stay 64 (+64 acc AGPR = 128-reg tier) to hold 4 waves/SIMD.
__global__ __launch_bounds__(1024, 4) void gemm_lse_kernel(const ushort* __restrict__ Vn,
                                                           const ushort* __restrict__ Un,
                                                           float* __restrict__ row_sum,
                                                           float* __restrict__ col_sum) {
  // buf b at b*65536: A[256][64] @0 (32K), B[256][64] @32768 (32K)
  __shared__ ushort Tile[65536];   // 128 KiB

  const int tid  = threadIdx.x;
  const int lane = tid & 63;
  const int wid  = tid >> 6;       // 0..15
  const int wr   = wid >> 2;       // 0..3 (64-row band)
  const int wc   = wid & 3;        // 0..3 (64-col band)
  const int l15  = lane & 15;
  const int lhi  = lane >> 4;      // 0..3
  const int sw7  = l15 & 7;

  // L2-residency map (R6): xcd owns fixed 4-ct stripe; rt streams 8/round
  const int bid  = blockIdx.x;
  const int xcd  = bid & 7;
  const int x    = bid >> 3;               // 0..127
  const int rt   = x >> 2;                 // 0..31
  const int ct   = xcd * 4 + (x & 3);      // fixed stripe
  const int br   = rt << 8;
  const int bc   = ct << 8;

  // ---- staging geometry: per matrix per K-tile = 2 issues x 1024 thr x 16B ----
  const int rr  = tid >> 3;                // 0..127
  const int seg = (tid & 7) ^ (rr & 7);    // inverse-swizzled source seg
  const ushort* gA[2]; const ushort* gB[2];
#pragma unroll
  for (int i = 0; i < 2; ++i) {
    gA[i] = Vn + (size_t)(br + i * 128 + rr) * DIM + seg * 8;
    gB[i] = Un + (size_t)(bc + i * 128 + rr) * DIM + seg * 8;
  }

  auto stg4 = [&](int buf, int kt) {   // whole K-tile kt -> buf (4 glds/thread)
#pragma unroll
    for (int i = 0; i < 2; ++i)
      __builtin_amdgcn_global_load_lds(
          (const __attribute__((address_space(1))) unsigned int*)(gA[i] + kt * 64),
          (__attribute__((address_space(3))) unsigned int*)((char*)Tile + buf * 65536 + i * 16384 + wid * 1024),
          16, 0, 0);
#pragma unroll
    for (int i = 0; i < 2; ++i)
      __builtin_amdgcn_global_load_lds(
          (const __attribute__((address_space(1))) unsigned int*)(gB[i] + kt * 64),
          (__attribute__((address_space(3))) unsigned int*)((char*)Tile + buf * 65536 + 32768 + i * 16384 + wid * 1024),
          16, 0, 0);
  };

  // ---- LDS read bases; physical slot = ((kk<<2)|lhi) ^ sw7 ----
  const char* TB = (const char*)Tile;
  const int sl0  = ((0 | lhi) ^ sw7) * 16;
  const int sl1  = ((4 | lhi) ^ sw7) * 16;
  const int aoff = (wr * 64 + l15) * 128;
  const int boff = (wc * 64 + l15) * 128;
  const char* pA[2] = { TB + aoff,          TB + 65536 + aoff };
  const char* pB[2] = { TB + 32768 + boff,  TB + 98304 + boff };

  f32x4 acc[4][4];
#pragma unroll
  for (int m = 0; m < 4; ++m)
#pragma unroll
    for (int n = 0; n < 4; ++n) acc[m][n] = (f32x4){0.f, 0.f, 0.f, 0.f};

  // prologue: tiles 0,1 staged (8 glds); tile0 landed at vmcnt(4)
  stg4(0, 0); stg4(1, 1);
  asm volatile("s_waitcnt vmcnt(4)" ::: "memory");
  __builtin_amdgcn_s_barrier();
  asm volatile("" ::: "memory");

#pragma unroll
  for (int j = 0; j < NKT; ++j) {
    const int b = j & 1;

    bf16x8 A0[4], B0[4], A1[4], B1[4];
    // kk0: read + 16 MFMA (compiler interleaves with counted lgkm)
#pragma unroll
    for (int m = 0; m < 4; ++m) A0[m] = *(const bf16x8*)(pA[b] + m * 2048 + sl0);
#pragma unroll
    for (int n = 0; n < 4; ++n) B0[n] = *(const bf16x8*)(pB[b] + n * 2048 + sl0);
    __builtin_amdgcn_s_setprio(1);
#pragma unroll
    for (int m = 0; m < 4; ++m)
#pragma unroll
      for (int n = 0; n < 4; ++n)
        acc[m][n] = __builtin_amdgcn_mfma_f32_16x16x32_bf16(A0[m], B0[n], acc[m][n], 0, 0, 0);
    __builtin_amdgcn_s_setprio(0);

    // kk1: read + 16 MFMA
#pragma unroll
    for (int m = 0; m < 4; ++m) A1[m] = *(const bf16x8*)(pA[b] + m * 2048 + sl1);
#pragma unroll
    for (int n = 0; n < 4; ++n) B1[n] = *(const bf16x8*)(pB[b] + n * 2048 + sl1);
    __builtin_amdgcn_s_setprio(1);
#pragma unroll
    for (int m = 0; m < 4; ++m)
#pragma unroll
      for (int n = 0; n < 4; ++n)
        acc[m][n] = __builtin_amdgcn_mfma_f32_16x16x32_bf16(A1[m], B1[n], acc[m][n], 0, 0, 0);
    __builtin_amdgcn_s_setprio(0);

    // ---- single-barrier boundary ----
    if (j + 2 < NKT) {
      asm volatile("s_waitcnt vmcnt(0) lgkmcnt(0)" ::: "memory");  // cold: covers loads 1 K-tile old + this tile's reads
      __builtin_amdgcn_s_barrier();
      asm volatile("" ::: "memory");
      stg4(b, j + 2);                                              // WAR-safe after bar; flies across next tile
    } else if (j == NKT - 2) {
      asm volatile("s_waitcnt vmcnt(0) lgkmcnt(0)" ::: "memory");  // tile 7 landed
      __builtin_amdgcn_s_barrier();
      asm volatile("" ::: "memory");
    }
    // j == NKT-1: fall through to epilogue
  }

  // ---- epilogue: exp(sim-10), row/col partial sums ----
  float* Red = (float*)Tile;

#pragma unroll
  for (int m = 0; m < 4; ++m)
#pragma unroll
    for (int n = 0; n < 4; ++n) {
      f32x4 v = acc[m][n];
#pragma unroll
      for (int r = 0; r < 4; ++r) v[r] = __builtin_amdgcn_exp2f((v[r] - 1.0f) * C_EXPSCALE);
      acc[m][n] = v;
    }

  __syncthreads();   // all frag reads done before Red overwrites Tile

  // rows: row_local = wr*64 + m*16 + lhi*4 + r; sum over wave's 64 cols
#pragma unroll
  for (int m = 0; m < 4; ++m)
#pragma unroll
    for (int r = 0; r < 4; ++r) {
      float s = acc[m][0][r] + acc[m][1][r] + acc[m][2][r] + acc[m][3][r];
      s += __shfl_xor(s, 1, 64);
      s += __shfl_xor(s, 2, 64);
      s += __shfl_xor(s, 4, 64);
      s += __shfl_xor(s, 8, 64);
      if (l15 == 0) Red[wc * 256 + wr * 64 + m * 16 + lhi * 4 + r] = s;
    }
  // cols: col_local = wc*64 + n*16 + l15; sum over wave's 64 rows
#pragma unroll
  for (int n = 0; n < 4; ++n) {
    float s = 0.f;
#pragma unroll
    for (int m = 0; m < 4; ++m)
      s += acc[m][n][0] + acc[m][n][1] + acc[m][n][2] + acc[m][n][3];
    s += __shfl_xor(s, 16, 64);
    s += __shfl_xor(s, 32, 64);
    if (lane < 16) Red[1024 + wr * 256 + wc * 64 + n * 16 + lane] = s;
  }
  __syncthreads();

  if (tid < 256) {
    float s = Red[tid] + Red[256 + tid] + Red[512 + tid] + Red[768 + tid];
    atomicAdd(&row_sum[br + tid], s);
  } else if (tid < 512) {
    const int c = tid - 256;
    float s = Red[1024 + c] + Red[1280 + c] + Red[1536 + c] + Red[1792 + c];
    atomicAdd(&col_sum[bc + c], s);
  }
}

// ---------------- finalize ----------------
__global__ __launch_bounds__(1024) void finalize_kernel(const float* __restrict__ row_sum,
                                                        const float* __restrict__ col_sum,
                                                        const float* __restrict__ diag,
                                                        float* __restrict__ out) {
  __shared__ float sred[1024];
  float acc = 0.0f;
  for (int i = threadIdx.x; i < N_ROWS; i += 1024) {
    const float lse_r = 10.0f + logf(row_sum[i]);
    const float lse_c = 10.0f + logf(col_sum[i]);
    acc += 0.75f * lse_r + 0.25f * lse_c - diag[i];
  }
  sred[threadIdx.x] = acc;
  __syncthreads();
  for (int s = 512; s > 0; s >>= 1) {
    if ((int)threadIdx.x < s) sred[threadIdx.x] += sred[threadIdx.x + s];
    __syncthreads();
  }
  if (threadIdx.x == 0) out[0] = sred[0] / (float)N_ROWS;
}

extern "C" void kernel_launch(void* const* d_in, const int* in_sizes, int n_in,
                              void* d_out, int out_size, void* d_ws, size_t ws_size,
                              hipStream_t stream) {
  const float* V = (const float*)d_in[0];
  const float* U = (const float*)d_in[1];
  float* out = (float*)d_out;

  char* ws = (char*)d_ws;
  ushort* Vn      = (ushort*)(ws);
  ushort* Un      = (ushort*)(ws + 8388608);
  float*  diag    = (float*)(ws + 16777216);
  float*  row_sum = (float*)(ws + 16777216 + 32768);
  float*  col_sum = (float*)(ws + 16777216 + 65536);

  prep_kernel<<<N_ROWS / 4, 256, 0, stream>>>(V, U, Vn, Un, diag, row_sum, col_sum);
  gemm_lse_kernel<<<(N_ROWS / 256) * (N_ROWS / 256), 1024, 0, stream>>>(Vn, Un, row_sum, col_sum);
  finalize_kernel<<<1, 1024, 0, stream>>>(row_sum, col_sum, diag, out);
}